// Round 1
// baseline (285.966 us; speedup 1.0000x reference)
//
#include <hip/hip_runtime.h>
#include <hip/hip_bf16.h>
#include <cstdint>
#include <cstddef>

// GlobalFluxTracker: B=8, T=4096, D=256.
// Decomposition:
//   K0: convert x_re/x_im (f32) -> Xcat bf16 [32768 x 512]
//   KW: convert weights -> bf16; build Wc=[Wo;Wg] [768x512], bc=[bo;bg]
//   G1: U = Xcat @ Wm^T + bm   (bf16 out, [32768 x 512])
//   S1/S2/S3: chunked complex scan s_t = d*s_{t-1} + u_t, in-place over U (bf16)
//   G2: OUT = S @ Wc^T + bc, sigmoid-clip cols >= 512   (f32 out, [32768 x 768])

typedef __bf16 bf16;
typedef __bf16 bf16x4 __attribute__((ext_vector_type(4)));
typedef __bf16 bf16x8 __attribute__((ext_vector_type(8)));
typedef float floatx4 __attribute__((ext_vector_type(4)));

#define NB 8
#define NT 4096
#define ND 256
#define BT (NB * NT)       // 32768
#define TWOD 512
#define CHUNK 128          // scan chunk length
#define NCHUNK (NT / CHUNK) // 32

static __device__ __forceinline__ float sigmoidf_(float x) {
  return 1.0f / (1.0f + __expf(-x));
}

static __device__ __forceinline__ void async_copy16(const void* g, void* l) {
  __builtin_amdgcn_global_load_lds(
      (__attribute__((address_space(1))) void*)g,
      (__attribute__((address_space(3))) void*)l, 16, 0, 0);
}

// ---------------------------------------------------------------- converts

__global__ void k_convert_x(const float* __restrict__ xr,
                            const float* __restrict__ xi,
                            bf16* __restrict__ X) {
  const int idx = (blockIdx.x * 256 + threadIdx.x) * 4; // over [BT*ND]
  const int row = idx >> 8;
  const int dd = idx & 255;
  const float4 vr = *(const float4*)(xr + idx);
  const float4 vi = *(const float4*)(xi + idx);
  bf16x4 br, bi;
  br[0] = (bf16)vr.x; br[1] = (bf16)vr.y; br[2] = (bf16)vr.z; br[3] = (bf16)vr.w;
  bi[0] = (bf16)vi.x; bi[1] = (bf16)vi.y; bi[2] = (bf16)vi.z; bi[3] = (bf16)vi.w;
  *(bf16x4*)(X + (size_t)row * TWOD + dd) = br;
  *(bf16x4*)(X + (size_t)row * TWOD + ND + dd) = bi;
}

__global__ void k_prep_weights(const float* __restrict__ Wm,
                               const float* __restrict__ Wo,
                               const float* __restrict__ Wg,
                               const float* __restrict__ bo,
                               const float* __restrict__ bg,
                               bf16* __restrict__ Wm_b,
                               bf16* __restrict__ Wc_b,
                               float* __restrict__ bc) {
  const int i = blockIdx.x * 256 + threadIdx.x; // 0..262143
  Wm_b[i] = (bf16)Wm[i];
  Wc_b[i] = (bf16)Wo[i];                         // rows 0..511 of Wc
  if (i < 131072) Wc_b[262144 + i] = (bf16)Wg[i]; // rows 512..767
  if (i < 512) bc[i] = bo[i];
  if (i < 256) bc[512 + i] = bg[i];
}

// ---------------------------------------------------------------- GEMM (NT form)
// C[m,n] = sum_k A[m,k] * Bw[n,k] + bias[n]
// MODE 0: store bf16 (U). MODE 1: store f32, sigmoid-clip for col >= actStart.
template <int MODE>
__global__ __launch_bounds__(256, 2) void gemm_bt(
    const bf16* __restrict__ A, const bf16* __restrict__ Bw,
    const float* __restrict__ bias, void* __restrict__ Cout,
    const int K, const int N, const int actStart) {
  __shared__ __align__(16) bf16 As[128 * 32];
  __shared__ __align__(16) bf16 Bs[128 * 32];
  const int tid = threadIdx.x;
  const int wave = tid >> 6;
  const int lane = tid & 63;
  const int quad = lane >> 4;
  const int l16 = lane & 15;
  const int m0 = blockIdx.y * 128;
  const int n0 = blockIdx.x * 128;
  const int wm = (wave >> 1) * 64;
  const int wn = (wave & 1) * 64;

  floatx4 acc[4][4];
#pragma unroll
  for (int i = 0; i < 4; ++i)
#pragma unroll
    for (int j = 0; j < 4; ++j) acc[i][j] = (floatx4)0.0f;

  for (int k0 = 0; k0 < K; k0 += 32) {
    __syncthreads(); // previous tile's LDS reads complete
#pragma unroll
    for (int i = 0; i < 2; ++i) {
      const int seg = i * 4 + wave;        // 0..7, wave-uniform
      const int f = seg * 512 + lane * 8;  // flat bf16 elem in 128x32 tile
      const int row = f >> 5;
      const int kk = f & 31;
      async_copy16(A + (size_t)(m0 + row) * K + (k0 + kk), As + seg * 512);
      async_copy16(Bw + (size_t)(n0 + row) * K + (k0 + kk), Bs + seg * 512);
    }
    __syncthreads(); // drains vmcnt -> LDS tiles visible

    bf16x8 af[4], bfr[4];
#pragma unroll
    for (int mi = 0; mi < 4; ++mi)
      af[mi] = *(const bf16x8*)(As + (wm + mi * 16 + l16) * 32 + quad * 8);
#pragma unroll
    for (int ni = 0; ni < 4; ++ni)
      bfr[ni] = *(const bf16x8*)(Bs + (wn + ni * 16 + l16) * 32 + quad * 8);
#pragma unroll
    for (int mi = 0; mi < 4; ++mi)
#pragma unroll
      for (int ni = 0; ni < 4; ++ni)
        acc[mi][ni] = __builtin_amdgcn_mfma_f32_16x16x32_bf16(
            af[mi], bfr[ni], acc[mi][ni], 0, 0, 0);
  }

  // epilogue: C/D layout col = lane&15, row = quad*4 + reg
#pragma unroll
  for (int mi = 0; mi < 4; ++mi) {
    const int rb = m0 + wm + mi * 16 + quad * 4;
#pragma unroll
    for (int ni = 0; ni < 4; ++ni) {
      const int col = n0 + wn + ni * 16 + l16;
      const float bb = bias[col];
      if (MODE == 0) {
        bf16* C = (bf16*)Cout;
#pragma unroll
        for (int r = 0; r < 4; ++r)
          C[(size_t)(rb + r) * N + col] = (bf16)(acc[mi][ni][r] + bb);
      } else {
        float* C = (float*)Cout;
#pragma unroll
        for (int r = 0; r < 4; ++r) {
          float v = acc[mi][ni][r] + bb;
          if (col >= actStart) v = fminf(fmaxf(sigmoidf_(v), 0.01f), 0.99f);
          C[(size_t)(rb + r) * N + col] = v;
        }
      }
    }
  }
}

// ---------------------------------------------------------------- scan
// channel (b,d): s_t = (dr + i*di) * s_{t-1} + (ur_t + i*ui_t)
// pass1: per-chunk local scan from 0 -> final state F[b,c,d]
__global__ void k_scan_pass1(const bf16* __restrict__ U,
                             const float* __restrict__ decay_re,
                             const float* __restrict__ decay_im,
                             float* __restrict__ Fre, float* __restrict__ Fim) {
  const int d = threadIdx.x;  // 0..255
  const int c = blockIdx.x;   // 0..31
  const int b = blockIdx.y;   // 0..7
  const float dr = sigmoidf_(decay_re[d]);
  const float di = decay_im[d];
  float sr = 0.f, si = 0.f;
  const size_t rowbase = (size_t)b * NT + (size_t)c * CHUNK;
  const bf16* Ur = U + rowbase * TWOD + d;
#pragma unroll 4
  for (int j = 0; j < CHUNK; ++j) {
    const float ur = (float)Ur[(size_t)j * TWOD];
    const float ui = (float)Ur[(size_t)j * TWOD + ND];
    const float nr = sr * dr - si * di + ur;
    const float ni = sr * di + si * dr + ui;
    sr = nr; si = ni;
  }
  const int o = (b * NCHUNK + c) * ND + d;
  Fre[o] = sr; Fim[o] = si;
}

// pass2: sequential over chunks (per channel) -> init state per chunk
__global__ void k_scan_pass2(const float* __restrict__ Fre,
                             const float* __restrict__ Fim,
                             const float* __restrict__ s0_re,
                             const float* __restrict__ s0_im,
                             const float* __restrict__ decay_re,
                             const float* __restrict__ decay_im,
                             float* __restrict__ Ire, float* __restrict__ Iim) {
  const int d = threadIdx.x;
  const int b = blockIdx.x;
  const float dr = sigmoidf_(decay_re[d]);
  const float di = decay_im[d];
  // dL = (dr + i*di)^CHUNK via 7 squarings (CHUNK=128)
  float pr = dr, pi = di;
#pragma unroll
  for (int i = 0; i < 7; ++i) {
    const float nr = pr * pr - pi * pi;
    const float ni = 2.f * pr * pi;
    pr = nr; pi = ni;
  }
  float sr = s0_re[b * ND + d];
  float si = s0_im[b * ND + d];
  for (int c = 0; c < NCHUNK; ++c) {
    const int o = (b * NCHUNK + c) * ND + d;
    Ire[o] = sr; Iim[o] = si;
    const float nr = sr * pr - si * pi + Fre[o];
    const float ni = sr * pi + si * pr + Fim[o];
    sr = nr; si = ni;
  }
}

// pass3: recompute local scans with true init, overwrite U (in place) with s_cat bf16
__global__ void k_scan_pass3(bf16* __restrict__ U,
                             const float* __restrict__ decay_re,
                             const float* __restrict__ decay_im,
                             const float* __restrict__ Ire,
                             const float* __restrict__ Iim) {
  const int d = threadIdx.x;
  const int c = blockIdx.x;
  const int b = blockIdx.y;
  const float dr = sigmoidf_(decay_re[d]);
  const float di = decay_im[d];
  const int o = (b * NCHUNK + c) * ND + d;
  float sr = Ire[o], si = Iim[o];
  const size_t rowbase = (size_t)b * NT + (size_t)c * CHUNK;
  bf16* Ur = U + rowbase * TWOD + d;
#pragma unroll 4
  for (int j = 0; j < CHUNK; ++j) {
    const float ur = (float)Ur[(size_t)j * TWOD];
    const float ui = (float)Ur[(size_t)j * TWOD + ND];
    const float nr = sr * dr - si * di + ur;
    const float ni = sr * di + si * dr + ui;
    sr = nr; si = ni;
    Ur[(size_t)j * TWOD] = (bf16)nr;
    Ur[(size_t)j * TWOD + ND] = (bf16)ni;
  }
}

// ---------------------------------------------------------------- launch

extern "C" void kernel_launch(void* const* d_in, const int* in_sizes, int n_in,
                              void* d_out, int out_size, void* d_ws, size_t ws_size,
                              hipStream_t stream) {
  const float* x_re = (const float*)d_in[0];
  const float* x_im = (const float*)d_in[1];
  const float* s0_re = (const float*)d_in[2];
  const float* s0_im = (const float*)d_in[3];
  const float* decay_re = (const float*)d_in[4];
  const float* decay_im = (const float*)d_in[5];
  const float* Wm = (const float*)d_in[6];
  const float* bm = (const float*)d_in[7];
  const float* Wo = (const float*)d_in[8];
  const float* bo = (const float*)d_in[9];
  const float* Wg = (const float*)d_in[10];
  const float* bg = (const float*)d_in[11];

  char* ws = (char*)d_ws;
  const size_t XCAT_OFF = 0;                         // 32 MB
  const size_t U_OFF = 33554432;                     // 32 MB
  const size_t WM_OFF = 67108864;                    // 512 KB
  const size_t WC_OFF = WM_OFF + 524288;             // 768 KB
  const size_t BC_OFF = WC_OFF + 786432;             // 3 KB (+pad)
  const size_t FRE_OFF = BC_OFF + 4096;
  const size_t FIM_OFF = FRE_OFF + 262144;
  const size_t IRE_OFF = FIM_OFF + 262144;
  const size_t IIM_OFF = IRE_OFF + 262144;

  bf16* Xcat = (bf16*)(ws + XCAT_OFF);
  bf16* U = (bf16*)(ws + U_OFF);
  bf16* Wm_b = (bf16*)(ws + WM_OFF);
  bf16* Wc_b = (bf16*)(ws + WC_OFF);
  float* bc = (float*)(ws + BC_OFF);
  float* Fre = (float*)(ws + FRE_OFF);
  float* Fim = (float*)(ws + FIM_OFF);
  float* Ire = (float*)(ws + IRE_OFF);
  float* Iim = (float*)(ws + IIM_OFF);

  float* out = (float*)d_out;

  // K0: x -> bf16 Xcat   (BT*ND/4/256 = 8192 blocks)
  k_convert_x<<<dim3(8192), 256, 0, stream>>>(x_re, x_im, Xcat);
  // KW: weights
  k_prep_weights<<<dim3(1024), 256, 0, stream>>>(Wm, Wo, Wg, bo, bg, Wm_b, Wc_b, bc);
  // G1: U = Xcat @ Wm^T + bm  (grid: N-tiles x M-tiles = 4 x 256)
  gemm_bt<0><<<dim3(4, 256), 256, 0, stream>>>(Xcat, Wm_b, bm, U, 512, 512, 0);
  // scan
  k_scan_pass1<<<dim3(NCHUNK, NB), ND, 0, stream>>>(U, decay_re, decay_im, Fre, Fim);
  k_scan_pass2<<<dim3(NB), ND, 0, stream>>>(Fre, Fim, s0_re, s0_im, decay_re, decay_im, Ire, Iim);
  k_scan_pass3<<<dim3(NCHUNK, NB), ND, 0, stream>>>(U, decay_re, decay_im, Ire, Iim);
  // G2: OUT = S @ Wc^T + bc, sigmoid-clip cols >= 512  (grid: 6 x 256)
  gemm_bt<1><<<dim3(6, 256), 256, 0, stream>>>(U, Wc_b, bc, d_out, 512, 768, 512);
}

// Round 2
// 266.527 us; speedup vs baseline: 1.0729x; 1.0729x over previous
//
#include <hip/hip_runtime.h>
#include <hip/hip_bf16.h>
#include <cstdint>
#include <cstddef>

// GlobalFluxTracker: B=8, T=4096, D=256.
//   K0: convert x_re/x_im (f32) -> Xcat bf16 [32768 x 512]; weights -> bf16
//   G1: U = Xcat @ Wm^T + bm   (bf16 out, [32768 x 512])
//   S1/S2/S3: chunked complex scan s_t = d*s_{t-1} + u_t, in-place over U (bf16)
//   G2: OUT = S @ [Wo;Wg]^T + [bo;bg], sigmoid-clip cols >= 512  (f32, [32768 x 768])
//
// GEMM: 128x128 tile, BK=64, 16x16x32 bf16 MFMA.
//  - m-tiles on blockIdx.x (256 % 8 == 0): n-blocks sharing an A-tile land on
//    the same XCD -> A fetched ~once from HBM.
//  - global_load_lds width=16 with XOR-swizzled chunk permutation: LDS slot is
//    forced (base + lane*16), but the per-lane GLOBAL address is free, so chunk
//    c = (lane%8) ^ (row&7) makes fragment reads bank-conflict-free.

typedef __bf16 bf16;
typedef __bf16 bf16x4 __attribute__((ext_vector_type(4)));
typedef __bf16 bf16x8 __attribute__((ext_vector_type(8)));
typedef float floatx4 __attribute__((ext_vector_type(4)));

#define NB 8
#define NT 4096
#define ND 256
#define BT (NB * NT)        // 32768
#define TWOD 512
#define CHUNK 128           // scan chunk length
#define NCHUNK (NT / CHUNK) // 32

static __device__ __forceinline__ float sigmoidf_(float x) {
  return 1.0f / (1.0f + __expf(-x));
}

static __device__ __forceinline__ void async_copy16(const void* g, void* l) {
  __builtin_amdgcn_global_load_lds(
      (__attribute__((address_space(1))) void*)g,
      (__attribute__((address_space(3))) void*)l, 16, 0, 0);
}

// ---------------------------------------------------------------- converts
// blocks [0, 8192): convert x -> Xcat bf16. blocks [8192, 9216): weights.
__global__ void k_prep(const float* __restrict__ xr,
                       const float* __restrict__ xi,
                       const float* __restrict__ Wm,
                       const float* __restrict__ Wo,
                       const float* __restrict__ Wg,
                       const float* __restrict__ bo,
                       const float* __restrict__ bg,
                       bf16* __restrict__ X,
                       bf16* __restrict__ Wm_b,
                       bf16* __restrict__ Wc_b,
                       float* __restrict__ bc) {
  const int bid = blockIdx.x;
  if (bid < 8192) {
    const int idx = (bid * 256 + threadIdx.x) * 4; // over [BT*ND]
    const int row = idx >> 8;
    const int dd = idx & 255;
    const float4 vr = *(const float4*)(xr + idx);
    const float4 vi = *(const float4*)(xi + idx);
    bf16x4 br, bi;
    br[0] = (bf16)vr.x; br[1] = (bf16)vr.y; br[2] = (bf16)vr.z; br[3] = (bf16)vr.w;
    bi[0] = (bf16)vi.x; bi[1] = (bf16)vi.y; bi[2] = (bf16)vi.z; bi[3] = (bf16)vi.w;
    *(bf16x4*)(X + (size_t)row * TWOD + dd) = br;
    *(bf16x4*)(X + (size_t)row * TWOD + ND + dd) = bi;
  } else {
    const int i = (bid - 8192) * 256 + threadIdx.x; // 0..262143
    Wm_b[i] = (bf16)Wm[i];
    Wc_b[i] = (bf16)Wo[i];                          // rows 0..511 of Wc
    if (i < 131072) Wc_b[262144 + i] = (bf16)Wg[i]; // rows 512..767
    if (i < 512) bc[i] = bo[i];
    if (i < 256) bc[512 + i] = bg[i];
  }
}

// ---------------------------------------------------------------- GEMM (NT form)
// C[m,n] = sum_k A[m,k] * Bw[n,k] + bias[n]
// MODE 0: store bf16 (U). MODE 1: store f32, sigmoid-clip for col >= actStart.
template <int MODE>
__global__ __launch_bounds__(256) void gemm_bt(
    const bf16* __restrict__ A, const bf16* __restrict__ Bw,
    const float* __restrict__ bias, void* __restrict__ Cout,
    const int K, const int N, const int actStart) {
  __shared__ __align__(16) bf16 As[128 * 64]; // 16 KB, XOR-swizzled chunks
  __shared__ __align__(16) bf16 Bs[128 * 64];
  const int tid = threadIdx.x;
  const int wave = tid >> 6;
  const int lane = tid & 63;
  const int quad = lane >> 4;
  const int l16 = lane & 15;
  const int m0 = blockIdx.x * 128; // m on x: n-blocks of same m-tile -> same XCD
  const int n0 = blockIdx.y * 128;
  const int wm = (wave >> 1) * 64;
  const int wn = (wave & 1) * 64;

  // staging indices (per-lane global gather, contiguous LDS)
  const int srow = lane >> 3;                      // 0..7 within a segment
  const int schunk = (lane & 7) ^ (srow & 7);      // global 16B-chunk index

  floatx4 acc[4][4];
#pragma unroll
  for (int i = 0; i < 4; ++i)
#pragma unroll
    for (int j = 0; j < 4; ++j) acc[i][j] = (floatx4)0.0f;

  for (int k0 = 0; k0 < K; k0 += 64) {
    __syncthreads(); // previous tile's LDS reads complete
#pragma unroll
    for (int i = 0; i < 4; ++i) {
      const int seg = wave * 4 + i;        // 0..15, wave-uniform
      const int row = seg * 8 + srow;      // tile row 0..127
      async_copy16(A + (size_t)(m0 + row) * K + k0 + schunk * 8, As + seg * 512);
      async_copy16(Bw + (size_t)(n0 + row) * K + k0 + schunk * 8, Bs + seg * 512);
    }
    __syncthreads(); // drains vmcnt -> LDS tiles visible

#pragma unroll
    for (int s = 0; s < 2; ++s) {
      bf16x8 af[4], bfr[4];
#pragma unroll
      for (int mi = 0; mi < 4; ++mi) {
        const int row = wm + mi * 16 + l16;
        const int ch = ((s << 2) | quad) ^ (l16 & 7);
        af[mi] = *(const bf16x8*)(As + row * 64 + ch * 8);
      }
#pragma unroll
      for (int ni = 0; ni < 4; ++ni) {
        const int row = wn + ni * 16 + l16;
        const int ch = ((s << 2) | quad) ^ (l16 & 7);
        bfr[ni] = *(const bf16x8*)(Bs + row * 64 + ch * 8);
      }
#pragma unroll
      for (int mi = 0; mi < 4; ++mi)
#pragma unroll
        for (int ni = 0; ni < 4; ++ni)
          acc[mi][ni] = __builtin_amdgcn_mfma_f32_16x16x32_bf16(
              af[mi], bfr[ni], acc[mi][ni], 0, 0, 0);
    }
  }

  // epilogue: C/D layout col = lane&15, row = quad*4 + reg
#pragma unroll
  for (int mi = 0; mi < 4; ++mi) {
    const int rb = m0 + wm + mi * 16 + quad * 4;
#pragma unroll
    for (int ni = 0; ni < 4; ++ni) {
      const int col = n0 + wn + ni * 16 + l16;
      const float bb = bias[col];
      if (MODE == 0) {
        bf16* C = (bf16*)Cout;
#pragma unroll
        for (int r = 0; r < 4; ++r)
          C[(size_t)(rb + r) * N + col] = (bf16)(acc[mi][ni][r] + bb);
      } else {
        float* C = (float*)Cout;
#pragma unroll
        for (int r = 0; r < 4; ++r) {
          float v = acc[mi][ni][r] + bb;
          if (col >= actStart) v = fminf(fmaxf(sigmoidf_(v), 0.01f), 0.99f);
          C[(size_t)(rb + r) * N + col] = v;
        }
      }
    }
  }
}

// ---------------------------------------------------------------- scan
// channel (b,d): s_t = (dr + i*di) * s_{t-1} + (ur_t + i*ui_t)
// pass1: per-chunk local scan from 0 -> final state F[b,c,d]
__global__ void k_scan_pass1(const bf16* __restrict__ U,
                             const float* __restrict__ decay_re,
                             const float* __restrict__ decay_im,
                             float* __restrict__ Fre, float* __restrict__ Fim) {
  const int d = threadIdx.x;  // 0..255
  const int c = blockIdx.x;   // 0..31
  const int b = blockIdx.y;   // 0..7
  const float dr = sigmoidf_(decay_re[d]);
  const float di = decay_im[d];
  float sr = 0.f, si = 0.f;
  const size_t rowbase = (size_t)b * NT + (size_t)c * CHUNK;
  const bf16* Ur = U + rowbase * TWOD + d;
#pragma unroll 4
  for (int j = 0; j < CHUNK; ++j) {
    const float ur = (float)Ur[(size_t)j * TWOD];
    const float ui = (float)Ur[(size_t)j * TWOD + ND];
    const float nr = sr * dr - si * di + ur;
    const float ni = sr * di + si * dr + ui;
    sr = nr; si = ni;
  }
  const int o = (b * NCHUNK + c) * ND + d;
  Fre[o] = sr; Fim[o] = si;
}

// pass2: sequential over chunks (per channel) -> init state per chunk
__global__ void k_scan_pass2(const float* __restrict__ Fre,
                             const float* __restrict__ Fim,
                             const float* __restrict__ s0_re,
                             const float* __restrict__ s0_im,
                             const float* __restrict__ decay_re,
                             const float* __restrict__ decay_im,
                             float* __restrict__ Ire, float* __restrict__ Iim) {
  const int d = threadIdx.x;
  const int b = blockIdx.x;
  const float dr = sigmoidf_(decay_re[d]);
  const float di = decay_im[d];
  // dL = (dr + i*di)^CHUNK via 7 squarings (CHUNK=128)
  float pr = dr, pi = di;
#pragma unroll
  for (int i = 0; i < 7; ++i) {
    const float nr = pr * pr - pi * pi;
    const float ni = 2.f * pr * pi;
    pr = nr; pi = ni;
  }
  float sr = s0_re[b * ND + d];
  float si = s0_im[b * ND + d];
  for (int c = 0; c < NCHUNK; ++c) {
    const int o = (b * NCHUNK + c) * ND + d;
    Ire[o] = sr; Iim[o] = si;
    const float nr = sr * pr - si * pi + Fre[o];
    const float ni = sr * pi + si * pr + Fim[o];
    sr = nr; si = ni;
  }
}

// pass3: recompute local scans with true init, overwrite U (in place) with s_cat bf16
__global__ void k_scan_pass3(bf16* __restrict__ U,
                             const float* __restrict__ decay_re,
                             const float* __restrict__ decay_im,
                             const float* __restrict__ Ire,
                             const float* __restrict__ Iim) {
  const int d = threadIdx.x;
  const int c = blockIdx.x;
  const int b = blockIdx.y;
  const float dr = sigmoidf_(decay_re[d]);
  const float di = decay_im[d];
  const int o = (b * NCHUNK + c) * ND + d;
  float sr = Ire[o], si = Iim[o];
  const size_t rowbase = (size_t)b * NT + (size_t)c * CHUNK;
  bf16* Ur = U + rowbase * TWOD + d;
#pragma unroll 4
  for (int j = 0; j < CHUNK; ++j) {
    const float ur = (float)Ur[(size_t)j * TWOD];
    const float ui = (float)Ur[(size_t)j * TWOD + ND];
    const float nr = sr * dr - si * di + ur;
    const float ni = sr * di + si * dr + ui;
    sr = nr; si = ni;
    Ur[(size_t)j * TWOD] = (bf16)nr;
    Ur[(size_t)j * TWOD + ND] = (bf16)ni;
  }
}

// ---------------------------------------------------------------- launch

extern "C" void kernel_launch(void* const* d_in, const int* in_sizes, int n_in,
                              void* d_out, int out_size, void* d_ws, size_t ws_size,
                              hipStream_t stream) {
  const float* x_re = (const float*)d_in[0];
  const float* x_im = (const float*)d_in[1];
  const float* s0_re = (const float*)d_in[2];
  const float* s0_im = (const float*)d_in[3];
  const float* decay_re = (const float*)d_in[4];
  const float* decay_im = (const float*)d_in[5];
  const float* Wm = (const float*)d_in[6];
  const float* bm = (const float*)d_in[7];
  const float* Wo = (const float*)d_in[8];
  const float* bo = (const float*)d_in[9];
  const float* Wg = (const float*)d_in[10];
  const float* bg = (const float*)d_in[11];

  char* ws = (char*)d_ws;
  const size_t XCAT_OFF = 0;                         // 32 MB
  const size_t U_OFF = 33554432;                     // 32 MB
  const size_t WM_OFF = 67108864;                    // 512 KB
  const size_t WC_OFF = WM_OFF + 524288;             // 768 KB
  const size_t BC_OFF = WC_OFF + 786432;             // 3 KB (+pad)
  const size_t FRE_OFF = BC_OFF + 4096;
  const size_t FIM_OFF = FRE_OFF + 262144;
  const size_t IRE_OFF = FIM_OFF + 262144;
  const size_t IIM_OFF = IRE_OFF + 262144;

  bf16* Xcat = (bf16*)(ws + XCAT_OFF);
  bf16* U = (bf16*)(ws + U_OFF);
  bf16* Wm_b = (bf16*)(ws + WM_OFF);
  bf16* Wc_b = (bf16*)(ws + WC_OFF);
  float* bc = (float*)(ws + BC_OFF);
  float* Fre = (float*)(ws + FRE_OFF);
  float* Fim = (float*)(ws + FIM_OFF);
  float* Ire = (float*)(ws + IRE_OFF);
  float* Iim = (float*)(ws + IIM_OFF);

  // K0: converts (blocks 0..8191 x, 8192..9215 weights)
  k_prep<<<dim3(9216), 256, 0, stream>>>(x_re, x_im, Wm, Wo, Wg, bo, bg,
                                         Xcat, Wm_b, Wc_b, bc);
  // G1: U = Xcat @ Wm^T + bm  (grid: m-tiles x n-tiles = 256 x 4)
  gemm_bt<0><<<dim3(256, 4), 256, 0, stream>>>(Xcat, Wm_b, bm, U, 512, 512, 0);
  // scan
  k_scan_pass1<<<dim3(NCHUNK, NB), ND, 0, stream>>>(U, decay_re, decay_im, Fre, Fim);
  k_scan_pass2<<<dim3(NB), ND, 0, stream>>>(Fre, Fim, s0_re, s0_im, decay_re, decay_im, Ire, Iim);
  k_scan_pass3<<<dim3(NCHUNK, NB), ND, 0, stream>>>(U, decay_re, decay_im, Ire, Iim);
  // G2: OUT = S @ Wc^T + bc, sigmoid-clip cols >= 512  (grid: 256 x 6)
  gemm_bt<1><<<dim3(256, 6), 256, 0, stream>>>(U, Wc_b, bc, d_out, 512, 768, 512);
}

// Round 3
// 259.776 us; speedup vs baseline: 1.1008x; 1.0260x over previous
//
#include <hip/hip_runtime.h>
#include <hip/hip_bf16.h>
#include <cstdint>
#include <cstddef>

// GlobalFluxTracker: B=8, T=4096, D=256.
//   prep: permute+convert weights to bf16 (interleaved channel layout)
//   G1:   U = [x_re|x_im] @ Wm_p^T + bm_p  (reads x f32 directly, bf16 out)
//         U cols interleaved: (ur_0, ui_0, ur_1, ui_1, ...)
//   scan: chunked complex scan s_t = d*s_{t-1} + u_t, CHUNK=32, in-place on U
//   G2:   OUT = S @ Wc_p^T + bc, sigmoid-clip cols >= 512  (f32 out)

typedef __bf16 bf16;
typedef __bf16 bf16x8 __attribute__((ext_vector_type(8)));
typedef float floatx4 __attribute__((ext_vector_type(4)));

#define NB 8
#define NT 4096
#define ND 256
#define BT (NB * NT)        // 32768
#define TWOD 512
#define CHUNK 32
#define NCHUNK (NT / CHUNK) // 128

static __device__ __forceinline__ float sigmoidf_(float x) {
  return 1.0f / (1.0f + __expf(-x));
}

static __device__ __forceinline__ void async_copy16(const void* g, void* l) {
  __builtin_amdgcn_global_load_lds(
      (__attribute__((address_space(1))) void*)g,
      (__attribute__((address_space(3))) void*)l, 16, 0, 0);
}

union U32BF2 { unsigned int u; __bf16 h[2]; };

// ---------------------------------------------------------------- prep
// Interleave permutation: channel d -> cols/rows (2d, 2d+1).
//   Wm_p[2d+e][k] = Wm[d + 256e][k]   (row permutation)
//   Wc_p[n][2d+e] = Wc[n][d + 256e]   (K/col permutation), Wc = [Wo; Wg]
//   bm_p[2d+e]    = bm[d + 256e]
__global__ void k_prep(const float* __restrict__ Wm,
                       const float* __restrict__ bm,
                       const float* __restrict__ Wo,
                       const float* __restrict__ Wg,
                       const float* __restrict__ bo,
                       const float* __restrict__ bg,
                       bf16* __restrict__ Wm_b,
                       bf16* __restrict__ Wc_b,
                       float* __restrict__ bm_p,
                       float* __restrict__ bc) {
  const int i = blockIdx.x * 256 + threadIdx.x; // 0..262143
  {
    const int r = i >> 9, c = i & 511;
    const int sr = (r >> 1) + (r & 1) * 256;
    Wm_b[i] = (bf16)Wm[sr * 512 + c];
  }
  {
    const int r = i >> 9, c = i & 511;
    const int sc = (c >> 1) + (c & 1) * 256;
    Wc_b[i] = (bf16)Wo[r * 512 + sc];                           // rows 0..511
    if (i < 131072) Wc_b[262144 + i] = (bf16)Wg[r * 512 + sc];  // rows 512..767
  }
  if (i < 512) { bm_p[i] = bm[(i >> 1) + (i & 1) * 256]; bc[i] = bo[i]; }
  if (i < 256) bc[512 + i] = bg[i];
}

// ---------------------------------------------------------------- G1
// U[m, n] = sum_k Xcat[m,k] * Wm_p[n,k] + bm_p[n]; Xcat = [x_re | x_im] f32.
// 128x128 tile, BK=64. A staged manually (f32 load -> cvt -> ds_write_b128),
// B staged via global_load_lds. Both use chunk-XOR layout: slot s of row r
// holds global 16B-chunk s^(r&7); frag read chunk kc at slot kc^(row&7).
__global__ __launch_bounds__(256) void gemm1(
    const float* __restrict__ xre, const float* __restrict__ xim,
    const bf16* __restrict__ Bw, const float* __restrict__ bias,
    bf16* __restrict__ C) {
  __shared__ __align__(16) bf16 As[128 * 64]; // 16 KB
  __shared__ __align__(16) bf16 Bs[128 * 64]; // 16 KB
  const int tid = threadIdx.x;
  const int wave = tid >> 6;
  const int lane = tid & 63;
  const int quad = lane >> 4;
  const int l16 = lane & 15;
  const int m0 = blockIdx.x * 128; // m on x -> same A-tile shares XCD
  const int n0 = blockIdx.y * 128;
  const int wm = (wave >> 1) * 64;
  const int wn = (wave & 1) * 64;
  const int srow = lane >> 3;
  const int schunk = (lane & 7) ^ (srow & 7);
  const int ar = tid >> 3; // 0..31
  const int sg = tid & 7;

  floatx4 acc[4][4];
#pragma unroll
  for (int i = 0; i < 4; ++i)
#pragma unroll
    for (int j = 0; j < 4; ++j) acc[i][j] = (floatx4)0.0f;

  for (int k0 = 0; k0 < 512; k0 += 64) {
    const float* xs = (k0 < 256) ? xre : xim;
    const int xcol = k0 & 255;
    __syncthreads(); // previous tile's LDS reads complete
    // B: async global->LDS
#pragma unroll
    for (int i = 0; i < 4; ++i) {
      const int seg = wave * 4 + i;
      const int row = seg * 8 + srow;
      async_copy16(Bw + (size_t)(n0 + row) * 512 + k0 + schunk * 8, Bs + seg * 512);
    }
    // A: manual f32 load -> bf16 -> LDS
#pragma unroll
    for (int it = 0; it < 4; ++it) {
      const int r = ar + 32 * it;
      const int cg = sg ^ (r & 7);
      const float* src = xs + (size_t)(m0 + r) * 256 + xcol + cg * 8;
      const float4 f0 = *(const float4*)(src);
      const float4 f1 = *(const float4*)(src + 4);
      bf16x8 v;
      v[0] = (bf16)f0.x; v[1] = (bf16)f0.y; v[2] = (bf16)f0.z; v[3] = (bf16)f0.w;
      v[4] = (bf16)f1.x; v[5] = (bf16)f1.y; v[6] = (bf16)f1.z; v[7] = (bf16)f1.w;
      *(bf16x8*)(As + r * 64 + sg * 8) = v;
    }
    __syncthreads(); // drains vmcnt + lgkm -> tiles visible

#pragma unroll
    for (int s = 0; s < 2; ++s) {
      bf16x8 af[4], bfr[4];
#pragma unroll
      for (int mi = 0; mi < 4; ++mi) {
        const int row = wm + mi * 16 + l16;
        const int ch = ((s << 2) | quad) ^ (l16 & 7);
        af[mi] = *(const bf16x8*)(As + row * 64 + ch * 8);
      }
#pragma unroll
      for (int ni = 0; ni < 4; ++ni) {
        const int row = wn + ni * 16 + l16;
        const int ch = ((s << 2) | quad) ^ (l16 & 7);
        bfr[ni] = *(const bf16x8*)(Bs + row * 64 + ch * 8);
      }
#pragma unroll
      for (int mi = 0; mi < 4; ++mi)
#pragma unroll
        for (int ni = 0; ni < 4; ++ni)
          acc[mi][ni] = __builtin_amdgcn_mfma_f32_16x16x32_bf16(
              af[mi], bfr[ni], acc[mi][ni], 0, 0, 0);
    }
  }

#pragma unroll
  for (int mi = 0; mi < 4; ++mi) {
    const int rb = m0 + wm + mi * 16 + quad * 4;
#pragma unroll
    for (int ni = 0; ni < 4; ++ni) {
      const int col = n0 + wn + ni * 16 + l16;
      const float bb = bias[col];
#pragma unroll
      for (int r = 0; r < 4; ++r)
        C[(size_t)(rb + r) * TWOD + col] = (bf16)(acc[mi][ni][r] + bb);
    }
  }
}

// ---------------------------------------------------------------- G2
// OUT[m, n] = sum_c S[m,c] * Wc_p[n,c] + bc[n]; sigmoid-clip for n >= 512.
// 128x64 tile, BK=64, LDS 24 KB (6 blocks/CU cap).
__global__ __launch_bounds__(256) void gemm2(
    const bf16* __restrict__ A, const bf16* __restrict__ Bw,
    const float* __restrict__ bias, float* __restrict__ C) {
  __shared__ __align__(16) bf16 As[128 * 64]; // 16 KB
  __shared__ __align__(16) bf16 Bs[64 * 64];  // 8 KB
  const int tid = threadIdx.x;
  const int wave = tid >> 6;
  const int lane = tid & 63;
  const int quad = lane >> 4;
  const int l16 = lane & 15;
  const int m0 = blockIdx.x * 128;
  const int n0 = blockIdx.y * 64;
  const int wm = (wave >> 1) * 64;
  const int wn = (wave & 1) * 32;
  const int srow = lane >> 3;
  const int schunk = (lane & 7) ^ (srow & 7);

  floatx4 acc[4][2];
#pragma unroll
  for (int i = 0; i < 4; ++i)
#pragma unroll
    for (int j = 0; j < 2; ++j) acc[i][j] = (floatx4)0.0f;

  for (int k0 = 0; k0 < 512; k0 += 64) {
    __syncthreads();
#pragma unroll
    for (int i = 0; i < 4; ++i) {
      const int seg = wave * 4 + i;
      const int row = seg * 8 + srow;
      async_copy16(A + (size_t)(m0 + row) * 512 + k0 + schunk * 8, As + seg * 512);
    }
#pragma unroll
    for (int i = 0; i < 2; ++i) {
      const int seg = wave * 2 + i;
      const int row = seg * 8 + srow;
      async_copy16(Bw + (size_t)(n0 + row) * 512 + k0 + schunk * 8, Bs + seg * 512);
    }
    __syncthreads();

#pragma unroll
    for (int s = 0; s < 2; ++s) {
      bf16x8 af[4], bfr[2];
#pragma unroll
      for (int mi = 0; mi < 4; ++mi) {
        const int row = wm + mi * 16 + l16;
        const int ch = ((s << 2) | quad) ^ (l16 & 7);
        af[mi] = *(const bf16x8*)(As + row * 64 + ch * 8);
      }
#pragma unroll
      for (int ni = 0; ni < 2; ++ni) {
        const int row = wn + ni * 16 + l16;
        const int ch = ((s << 2) | quad) ^ (l16 & 7);
        bfr[ni] = *(const bf16x8*)(Bs + row * 64 + ch * 8);
      }
#pragma unroll
      for (int mi = 0; mi < 4; ++mi)
#pragma unroll
        for (int ni = 0; ni < 2; ++ni)
          acc[mi][ni] = __builtin_amdgcn_mfma_f32_16x16x32_bf16(
              af[mi], bfr[ni], acc[mi][ni], 0, 0, 0);
    }
  }

#pragma unroll
  for (int mi = 0; mi < 4; ++mi) {
    const int rb = m0 + wm + mi * 16 + quad * 4;
#pragma unroll
    for (int ni = 0; ni < 2; ++ni) {
      const int col = n0 + wn + ni * 16 + l16;
      const float bb = bias[col];
#pragma unroll
      for (int r = 0; r < 4; ++r) {
        float v = acc[mi][ni][r] + bb;
        if (col >= 512) v = fminf(fmaxf(sigmoidf_(v), 0.01f), 0.99f);
        C[(size_t)(rb + r) * 768 + col] = v;
      }
    }
  }
}

// ---------------------------------------------------------------- scan
// U interleaved: channel d at cols (2d, 2d+1) -> one aligned 4B word/step.
__global__ void k_scan_pass1(const bf16* __restrict__ U,
                             const float* __restrict__ decay_re,
                             const float* __restrict__ decay_im,
                             float* __restrict__ Fre, float* __restrict__ Fim) {
  const int d = threadIdx.x;  // 0..255
  const int c = blockIdx.x;   // 0..127
  const int b = blockIdx.y;   // 0..7
  const float dr = sigmoidf_(decay_re[d]);
  const float di = decay_im[d];
  float sr = 0.f, si = 0.f;
  const unsigned int* Ur = (const unsigned int*)
      (U + ((size_t)b * NT + (size_t)c * CHUNK) * TWOD + 2 * d);
#pragma unroll 4
  for (int j = 0; j < CHUNK; ++j) {
    U32BF2 cv; cv.u = Ur[(size_t)j * (TWOD / 2)];
    const float ur = (float)cv.h[0];
    const float ui = (float)cv.h[1];
    const float nr = sr * dr - si * di + ur;
    const float ni = sr * di + si * dr + ui;
    sr = nr; si = ni;
  }
  const int o = (b * NCHUNK + c) * ND + d;
  Fre[o] = sr; Fim[o] = si;
}

__global__ void k_scan_pass2(const float* __restrict__ Fre,
                             const float* __restrict__ Fim,
                             const float* __restrict__ s0_re,
                             const float* __restrict__ s0_im,
                             const float* __restrict__ decay_re,
                             const float* __restrict__ decay_im,
                             float* __restrict__ Ire, float* __restrict__ Iim) {
  const int d = threadIdx.x;
  const int b = blockIdx.x;
  const float dr = sigmoidf_(decay_re[d]);
  const float di = decay_im[d];
  float pr = dr, pi = di; // (dr + i*di)^CHUNK via 5 squarings (CHUNK=32)
#pragma unroll
  for (int i = 0; i < 5; ++i) {
    const float nr = pr * pr - pi * pi;
    const float ni = 2.f * pr * pi;
    pr = nr; pi = ni;
  }
  float sr = s0_re[b * ND + d];
  float si = s0_im[b * ND + d];
  for (int c = 0; c < NCHUNK; ++c) {
    const int o = (b * NCHUNK + c) * ND + d;
    Ire[o] = sr; Iim[o] = si;
    const float nr = sr * pr - si * pi + Fre[o];
    const float ni = sr * pi + si * pr + Fim[o];
    sr = nr; si = ni;
  }
}

__global__ void k_scan_pass3(bf16* __restrict__ U,
                             const float* __restrict__ decay_re,
                             const float* __restrict__ decay_im,
                             const float* __restrict__ Ire,
                             const float* __restrict__ Iim) {
  const int d = threadIdx.x;
  const int c = blockIdx.x;
  const int b = blockIdx.y;
  const float dr = sigmoidf_(decay_re[d]);
  const float di = decay_im[d];
  const int o = (b * NCHUNK + c) * ND + d;
  float sr = Ire[o], si = Iim[o];
  unsigned int* Ur = (unsigned int*)
      (U + ((size_t)b * NT + (size_t)c * CHUNK) * TWOD + 2 * d);
#pragma unroll 4
  for (int j = 0; j < CHUNK; ++j) {
    U32BF2 cv; cv.u = Ur[(size_t)j * (TWOD / 2)];
    const float ur = (float)cv.h[0];
    const float ui = (float)cv.h[1];
    const float nr = sr * dr - si * di + ur;
    const float ni = sr * di + si * dr + ui;
    sr = nr; si = ni;
    cv.h[0] = (bf16)nr; cv.h[1] = (bf16)ni;
    Ur[(size_t)j * (TWOD / 2)] = cv.u;
  }
}

// ---------------------------------------------------------------- launch

extern "C" void kernel_launch(void* const* d_in, const int* in_sizes, int n_in,
                              void* d_out, int out_size, void* d_ws, size_t ws_size,
                              hipStream_t stream) {
  const float* x_re = (const float*)d_in[0];
  const float* x_im = (const float*)d_in[1];
  const float* s0_re = (const float*)d_in[2];
  const float* s0_im = (const float*)d_in[3];
  const float* decay_re = (const float*)d_in[4];
  const float* decay_im = (const float*)d_in[5];
  const float* Wm = (const float*)d_in[6];
  const float* bm = (const float*)d_in[7];
  const float* Wo = (const float*)d_in[8];
  const float* bo = (const float*)d_in[9];
  const float* Wg = (const float*)d_in[10];
  const float* bg = (const float*)d_in[11];

  char* ws = (char*)d_ws;
  const size_t U_OFF = 0;                      // 32 MB
  const size_t WM_OFF = 33554432;              // 512 KB
  const size_t WC_OFF = WM_OFF + 524288;       // 768 KB
  const size_t BMP_OFF = WC_OFF + 786432;      // 2 KB (+pad)
  const size_t BC_OFF = BMP_OFF + 4096;        // 3 KB (+pad)
  const size_t FRE_OFF = BC_OFF + 4096;        // 1 MB each
  const size_t FIM_OFF = FRE_OFF + 1048576;
  const size_t IRE_OFF = FIM_OFF + 1048576;
  const size_t IIM_OFF = IRE_OFF + 1048576;

  bf16* U = (bf16*)(ws + U_OFF);
  bf16* Wm_b = (bf16*)(ws + WM_OFF);
  bf16* Wc_b = (bf16*)(ws + WC_OFF);
  float* bm_p = (float*)(ws + BMP_OFF);
  float* bc = (float*)(ws + BC_OFF);
  float* Fre = (float*)(ws + FRE_OFF);
  float* Fim = (float*)(ws + FIM_OFF);
  float* Ire = (float*)(ws + IRE_OFF);
  float* Iim = (float*)(ws + IIM_OFF);

  k_prep<<<dim3(1024), 256, 0, stream>>>(Wm, bm, Wo, Wg, bo, bg,
                                         Wm_b, Wc_b, bm_p, bc);
  gemm1<<<dim3(256, 4), 256, 0, stream>>>(x_re, x_im, Wm_b, bm_p, U);
  k_scan_pass1<<<dim3(NCHUNK, NB), ND, 0, stream>>>(U, decay_re, decay_im, Fre, Fim);
  k_scan_pass2<<<dim3(NB), ND, 0, stream>>>(Fre, Fim, s0_re, s0_im,
                                            decay_re, decay_im, Ire, Iim);
  k_scan_pass3<<<dim3(NCHUNK, NB), ND, 0, stream>>>(U, decay_re, decay_im, Ire, Iim);
  gemm2<<<dim3(256, 12), 256, 0, stream>>>(U, Wc_b, bc, (float*)d_out);
}

// Round 4
// 254.008 us; speedup vs baseline: 1.1258x; 1.0227x over previous
//
#include <hip/hip_runtime.h>
#include <hip/hip_bf16.h>
#include <cstdint>
#include <cstddef>

// GlobalFluxTracker: B=8, T=4096, D=256.
//   prep:  permute+convert weights to bf16 (interleaved channel layout)
//   G1:    U = [x_re|x_im] @ Wm_p^T + bm_p  (reads x f32 directly, bf16 out)
//          + FUSED local chunk scans (CHUNK=32, zero-init) -> F per (b,chunk,d)
//   scan2: parallel Hillis-Steele over 128 chunk-finals -> per-chunk init I
//   pass3: recompute local scans with true init, in-place U -> S (bf16)
//   G2:    OUT = S @ Wc_p^T + bc, sigmoid-clip cols >= 512  (f32 out)

typedef __bf16 bf16;
typedef __bf16 bf16x8 __attribute__((ext_vector_type(8)));
typedef float floatx4 __attribute__((ext_vector_type(4)));

#define NB 8
#define NT 4096
#define ND 256
#define BT (NB * NT)        // 32768
#define TWOD 512
#define CHUNK 32
#define NCHUNK (NT / CHUNK) // 128

static __device__ __forceinline__ float sigmoidf_(float x) {
  return 1.0f / (1.0f + __expf(-x));
}

static __device__ __forceinline__ void async_copy16(const void* g, void* l) {
  __builtin_amdgcn_global_load_lds(
      (__attribute__((address_space(1))) void*)g,
      (__attribute__((address_space(3))) void*)l, 16, 0, 0);
}

union U32BF2 { unsigned int u; __bf16 h[2]; };

// ---------------------------------------------------------------- prep
// Interleave permutation: channel d -> cols/rows (2d, 2d+1).
__global__ void k_prep(const float* __restrict__ Wm,
                       const float* __restrict__ bm,
                       const float* __restrict__ Wo,
                       const float* __restrict__ Wg,
                       const float* __restrict__ bo,
                       const float* __restrict__ bg,
                       bf16* __restrict__ Wm_b,
                       bf16* __restrict__ Wc_b,
                       float* __restrict__ bm_p,
                       float* __restrict__ bc) {
  const int i = blockIdx.x * 256 + threadIdx.x; // 0..262143
  {
    const int r = i >> 9, c = i & 511;
    const int sr = (r >> 1) + (r & 1) * 256;
    Wm_b[i] = (bf16)Wm[sr * 512 + c];
  }
  {
    const int r = i >> 9, c = i & 511;
    const int sc = (c >> 1) + (c & 1) * 256;
    Wc_b[i] = (bf16)Wo[r * 512 + sc];                           // rows 0..511
    if (i < 131072) Wc_b[262144 + i] = (bf16)Wg[r * 512 + sc];  // rows 512..767
  }
  if (i < 512) { bm_p[i] = bm[(i >> 1) + (i & 1) * 256]; bc[i] = bo[i]; }
  if (i < 256) bc[512 + i] = bg[i];
}

// ---------------------------------------------------------------- G1 (+local scan)
__global__ __launch_bounds__(256) void gemm1(
    const float* __restrict__ xre, const float* __restrict__ xim,
    const bf16* __restrict__ Bw, const float* __restrict__ bias,
    bf16* __restrict__ Cu,
    const float* __restrict__ decay_re, const float* __restrict__ decay_im,
    float* __restrict__ Fre, float* __restrict__ Fim) {
  __shared__ __align__(16) bf16 smem[128 * 128]; // 32 KB
  bf16* As = smem;            // 128x64 (16 KB)
  bf16* Bs = smem + 128 * 64; // 128x64 (16 KB)
  bf16* Us = smem;            // epilogue reuse: 128x128 bf16 tile
  const int tid = threadIdx.x;
  const int wave = tid >> 6;
  const int lane = tid & 63;
  const int quad = lane >> 4;
  const int l16 = lane & 15;
  const int m0 = blockIdx.x * 128; // m on x -> A-tile-sharing blocks same XCD
  const int n0 = blockIdx.y * 128;
  const int wm = (wave >> 1) * 64;
  const int wn = (wave & 1) * 64;
  const int srow = lane >> 3;
  const int schunk = (lane & 7) ^ (srow & 7);
  const int ar = tid >> 3; // 0..31
  const int sg = tid & 7;

  floatx4 acc[4][4];
#pragma unroll
  for (int i = 0; i < 4; ++i)
#pragma unroll
    for (int j = 0; j < 4; ++j) acc[i][j] = (floatx4)0.0f;

  for (int k0 = 0; k0 < 512; k0 += 64) {
    const float* xs = (k0 < 256) ? xre : xim;
    const int xcol = k0 & 255;
    __syncthreads();
    // B: async global->LDS (chunk-XOR swizzle)
#pragma unroll
    for (int i = 0; i < 4; ++i) {
      const int seg = wave * 4 + i;
      const int row = seg * 8 + srow;
      async_copy16(Bw + (size_t)(n0 + row) * 512 + k0 + schunk * 8, Bs + seg * 512);
    }
    // A: manual f32 load -> bf16 -> LDS (same swizzle)
#pragma unroll
    for (int it = 0; it < 4; ++it) {
      const int r = ar + 32 * it;
      const int cg = sg ^ (r & 7);
      const float* src = xs + (size_t)(m0 + r) * 256 + xcol + cg * 8;
      const float4 f0 = *(const float4*)(src);
      const float4 f1 = *(const float4*)(src + 4);
      bf16x8 v;
      v[0] = (bf16)f0.x; v[1] = (bf16)f0.y; v[2] = (bf16)f0.z; v[3] = (bf16)f0.w;
      v[4] = (bf16)f1.x; v[5] = (bf16)f1.y; v[6] = (bf16)f1.z; v[7] = (bf16)f1.w;
      *(bf16x8*)(As + r * 64 + sg * 8) = v;
    }
    __syncthreads();

#pragma unroll
    for (int s = 0; s < 2; ++s) {
      bf16x8 af[4], bfr[4];
#pragma unroll
      for (int mi = 0; mi < 4; ++mi) {
        const int row = wm + mi * 16 + l16;
        const int ch = ((s << 2) | quad) ^ (l16 & 7);
        af[mi] = *(const bf16x8*)(As + row * 64 + ch * 8);
      }
#pragma unroll
      for (int ni = 0; ni < 4; ++ni) {
        const int row = wn + ni * 16 + l16;
        const int ch = ((s << 2) | quad) ^ (l16 & 7);
        bfr[ni] = *(const bf16x8*)(Bs + row * 64 + ch * 8);
      }
#pragma unroll
      for (int mi = 0; mi < 4; ++mi)
#pragma unroll
        for (int ni = 0; ni < 4; ++ni)
          acc[mi][ni] = __builtin_amdgcn_mfma_f32_16x16x32_bf16(
              af[mi], bfr[ni], acc[mi][ni], 0, 0, 0);
    }
  }

  // ---- epilogue: bias add, stage bf16 tile to LDS
  __syncthreads(); // all MFMA-feeding LDS reads done before Us overwrite
#pragma unroll
  for (int mi = 0; mi < 4; ++mi) {
    const int rloc = wm + mi * 16 + quad * 4;
#pragma unroll
    for (int ni = 0; ni < 4; ++ni) {
      const int cloc = wn + ni * 16 + l16;
      const float bb = bias[n0 + cloc];
#pragma unroll
      for (int r = 0; r < 4; ++r)
        Us[(rloc + r) * 128 + cloc] = (bf16)(acc[mi][ni][r] + bb);
    }
  }
  __syncthreads();
  // coalesced b128 global store of U from LDS
  {
    bf16* dst = Cu + (size_t)m0 * TWOD + n0;
#pragma unroll
    for (int i = 0; i < 8; ++i) {
      const int e = i * 256 + tid;   // 16B-chunk index 0..2047
      const int row = e >> 4, ch = e & 15;
      *(bf16x8*)(dst + (size_t)row * TWOD + ch * 8) =
          *(const bf16x8*)(Us + row * 128 + ch * 8);
    }
  }
  // fused local scans (zero-init): 4 subchunks x 64 channels
  {
    const int sc = tid >> 6;  // 0..3 (wave-uniform)
    const int dd = tid & 63;  // 0..63
    const int d = (n0 >> 1) + dd;
    const float drr = sigmoidf_(decay_re[d]);
    const float dii = decay_im[d];
    float sr = 0.f, si = 0.f;
    const unsigned int* Up = (const unsigned int*)(Us + (sc * 32) * 128 + 2 * dd);
#pragma unroll 4
    for (int j = 0; j < 32; ++j) {
      U32BF2 cv; cv.u = Up[j * 64];
      const float ur = (float)cv.h[0];
      const float ui = (float)cv.h[1];
      const float nr = sr * drr - si * dii + ur;
      const float ni2 = sr * dii + si * drr + ui;
      sr = nr; si = ni2;
    }
    const int bidx = m0 >> 12;
    const int cchunk = ((m0 & 4095) >> 5) + sc;
    const int o = (bidx * NCHUNK + cchunk) * ND + d;
    Fre[o] = sr; Fim[o] = si;
  }
}

// ---------------------------------------------------------------- scan2 (parallel)
// Per (b,d): weighted inclusive scan of F over 128 chunks, multiplier P32.
// b_c = F_c + P32*b_{c-1}; init for chunk c: I_c = b_{c-1} + P32^c * s0.
__global__ void k_scan2(const float* __restrict__ Fre,
                        const float* __restrict__ Fim,
                        const float* __restrict__ s0_re,
                        const float* __restrict__ s0_im,
                        const float* __restrict__ decay_re,
                        const float* __restrict__ decay_im,
                        float* __restrict__ Ire, float* __restrict__ Iim) {
  const int c = threadIdx.x;  // 0..127
  const int d = blockIdx.x;   // 0..255
  const int b = blockIdx.y;   // 0..7
  const float drr = sigmoidf_(decay_re[d]);
  const float dii = decay_im[d];
  float wr = drr, wi = dii; // -> P32 via 5 squarings
#pragma unroll
  for (int i = 0; i < 5; ++i) {
    const float nr = wr * wr - wi * wi;
    const float ni = 2.f * wr * wi;
    wr = nr; wi = ni;
  }
  const int o = (b * NCHUNK + c) * ND + d;
  float vr = Fre[o], vi = Fim[o];
  float ar = 1.f, ai = 0.f;   // -> P32^c via binary decomposition of c
  __shared__ float lr[128], li[128];
#pragma unroll
  for (int k = 1; k < 128; k <<= 1) {
    lr[c] = vr; li[c] = vi;
    __syncthreads();
    const float tr = (c >= k) ? lr[c - k] : 0.f;
    const float ti = (c >= k) ? li[c - k] : 0.f;
    __syncthreads();
    vr += wr * tr - wi * ti;
    vi += wr * ti + wi * tr;
    if (c & k) {
      const float nar = ar * wr - ai * wi;
      ai = ar * wi + ai * wr;
      ar = nar;
    }
    const float nwr = wr * wr - wi * wi;
    wi = 2.f * wr * wi;
    wr = nwr;
  }
  // exclusive shift: I_c = b_{c-1} (b_{-1} = 0) + P32^c * s0
  lr[c] = vr; li[c] = vi;
  __syncthreads();
  float er = (c > 0) ? lr[c - 1] : 0.f;
  float ei = (c > 0) ? li[c - 1] : 0.f;
  const float s0r = s0_re[b * ND + d];
  const float s0i = s0_im[b * ND + d];
  er += ar * s0r - ai * s0i;
  ei += ar * s0i + ai * s0r;
  Ire[o] = er; Iim[o] = ei;
}

// ---------------------------------------------------------------- pass3
__global__ void k_scan_pass3(bf16* __restrict__ U,
                             const float* __restrict__ decay_re,
                             const float* __restrict__ decay_im,
                             const float* __restrict__ Ire,
                             const float* __restrict__ Iim) {
  const int d = threadIdx.x;
  const int c = blockIdx.x;
  const int b = blockIdx.y;
  const float dr = sigmoidf_(decay_re[d]);
  const float di = decay_im[d];
  const int o = (b * NCHUNK + c) * ND + d;
  float sr = Ire[o], si = Iim[o];
  unsigned int* Ur = (unsigned int*)
      (U + ((size_t)b * NT + (size_t)c * CHUNK) * TWOD + 2 * d);
#pragma unroll 4
  for (int j = 0; j < CHUNK; ++j) {
    U32BF2 cv; cv.u = Ur[(size_t)j * (TWOD / 2)];
    const float ur = (float)cv.h[0];
    const float ui = (float)cv.h[1];
    const float nr = sr * dr - si * di + ur;
    const float ni = sr * di + si * dr + ui;
    sr = nr; si = ni;
    cv.h[0] = (bf16)nr; cv.h[1] = (bf16)ni;
    Ur[(size_t)j * (TWOD / 2)] = cv.u;
  }
}

// ---------------------------------------------------------------- G2
__global__ __launch_bounds__(256) void gemm2(
    const bf16* __restrict__ A, const bf16* __restrict__ Bw,
    const float* __restrict__ bias, float* __restrict__ C) {
  __shared__ __align__(16) bf16 As[128 * 64]; // 16 KB
  __shared__ __align__(16) bf16 Bs[64 * 64];  // 8 KB
  const int tid = threadIdx.x;
  const int wave = tid >> 6;
  const int lane = tid & 63;
  const int quad = lane >> 4;
  const int l16 = lane & 15;
  const int m0 = blockIdx.x * 128;
  const int n0 = blockIdx.y * 64;
  const int wm = (wave >> 1) * 64;
  const int wn = (wave & 1) * 32;
  const int srow = lane >> 3;
  const int schunk = (lane & 7) ^ (srow & 7);

  floatx4 acc[4][2];
#pragma unroll
  for (int i = 0; i < 4; ++i)
#pragma unroll
    for (int j = 0; j < 2; ++j) acc[i][j] = (floatx4)0.0f;

  for (int k0 = 0; k0 < 512; k0 += 64) {
    __syncthreads();
#pragma unroll
    for (int i = 0; i < 4; ++i) {
      const int seg = wave * 4 + i;
      const int row = seg * 8 + srow;
      async_copy16(A + (size_t)(m0 + row) * 512 + k0 + schunk * 8, As + seg * 512);
    }
#pragma unroll
    for (int i = 0; i < 2; ++i) {
      const int seg = wave * 2 + i;
      const int row = seg * 8 + srow;
      async_copy16(Bw + (size_t)(n0 + row) * 512 + k0 + schunk * 8, Bs + seg * 512);
    }
    __syncthreads();

#pragma unroll
    for (int s = 0; s < 2; ++s) {
      bf16x8 af[4], bfr[2];
#pragma unroll
      for (int mi = 0; mi < 4; ++mi) {
        const int row = wm + mi * 16 + l16;
        const int ch = ((s << 2) | quad) ^ (l16 & 7);
        af[mi] = *(const bf16x8*)(As + row * 64 + ch * 8);
      }
#pragma unroll
      for (int ni = 0; ni < 2; ++ni) {
        const int row = wn + ni * 16 + l16;
        const int ch = ((s << 2) | quad) ^ (l16 & 7);
        bfr[ni] = *(const bf16x8*)(Bs + row * 64 + ch * 8);
      }
#pragma unroll
      for (int mi = 0; mi < 4; ++mi)
#pragma unroll
        for (int ni = 0; ni < 2; ++ni)
          acc[mi][ni] = __builtin_amdgcn_mfma_f32_16x16x32_bf16(
              af[mi], bfr[ni], acc[mi][ni], 0, 0, 0);
    }
  }

#pragma unroll
  for (int mi = 0; mi < 4; ++mi) {
    const int rb = m0 + wm + mi * 16 + quad * 4;
#pragma unroll
    for (int ni = 0; ni < 2; ++ni) {
      const int col = n0 + wn + ni * 16 + l16;
      const float bb = bias[col];
#pragma unroll
      for (int r = 0; r < 4; ++r) {
        float v = acc[mi][ni][r] + bb;
        if (col >= 512) v = fminf(fmaxf(sigmoidf_(v), 0.01f), 0.99f);
        C[(size_t)(rb + r) * 768 + col] = v;
      }
    }
  }
}

// ---------------------------------------------------------------- launch

extern "C" void kernel_launch(void* const* d_in, const int* in_sizes, int n_in,
                              void* d_out, int out_size, void* d_ws, size_t ws_size,
                              hipStream_t stream) {
  const float* x_re = (const float*)d_in[0];
  const float* x_im = (const float*)d_in[1];
  const float* s0_re = (const float*)d_in[2];
  const float* s0_im = (const float*)d_in[3];
  const float* decay_re = (const float*)d_in[4];
  const float* decay_im = (const float*)d_in[5];
  const float* Wm = (const float*)d_in[6];
  const float* bm = (const float*)d_in[7];
  const float* Wo = (const float*)d_in[8];
  const float* bo = (const float*)d_in[9];
  const float* Wg = (const float*)d_in[10];
  const float* bg = (const float*)d_in[11];

  char* ws = (char*)d_ws;
  const size_t U_OFF = 0;                      // 32 MB
  const size_t WM_OFF = 33554432;              // 512 KB
  const size_t WC_OFF = WM_OFF + 524288;       // 768 KB
  const size_t BMP_OFF = WC_OFF + 786432;      // 2 KB (+pad)
  const size_t BC_OFF = BMP_OFF + 4096;        // 3 KB (+pad)
  const size_t FRE_OFF = BC_OFF + 4096;        // 1 MB each
  const size_t FIM_OFF = FRE_OFF + 1048576;
  const size_t IRE_OFF = FIM_OFF + 1048576;
  const size_t IIM_OFF = IRE_OFF + 1048576;

  bf16* U = (bf16*)(ws + U_OFF);
  bf16* Wm_b = (bf16*)(ws + WM_OFF);
  bf16* Wc_b = (bf16*)(ws + WC_OFF);
  float* bm_p = (float*)(ws + BMP_OFF);
  float* bc = (float*)(ws + BC_OFF);
  float* Fre = (float*)(ws + FRE_OFF);
  float* Fim = (float*)(ws + FIM_OFF);
  float* Ire = (float*)(ws + IRE_OFF);
  float* Iim = (float*)(ws + IIM_OFF);

  k_prep<<<dim3(1024), 256, 0, stream>>>(Wm, bm, Wo, Wg, bo, bg,
                                         Wm_b, Wc_b, bm_p, bc);
  gemm1<<<dim3(256, 4), 256, 0, stream>>>(x_re, x_im, Wm_b, bm_p, U,
                                          decay_re, decay_im, Fre, Fim);
  k_scan2<<<dim3(ND, NB), NCHUNK, 0, stream>>>(Fre, Fim, s0_re, s0_im,
                                               decay_re, decay_im, Ire, Iim);
  k_scan_pass3<<<dim3(NCHUNK, NB), ND, 0, stream>>>(U, decay_re, decay_im, Ire, Iim);
  gemm2<<<dim3(256, 12), 256, 0, stream>>>(U, Wc_b, bc, (float*)d_out);
}